// Round 5
// baseline (304.960 us; speedup 1.0000x reference)
//
#include <hip/hip_runtime.h>

#define NB 16
#define NVEC 2048
#define NDIM 32
#define NW 4
#define NHID 128
#define NCLASS 10
#define MS 32               // m-splits for k_U (m-range 64 per block)
#define USIZE (129 * 32)    // U per b: rows 0..127 = fw2@V, row 128 = fb2^T@V
#define HSLICE ((size_t)NB * NVEC * NHID)   // h floats per layer

// tanh-approx GELU; validated absmax vs ref in prior sessions.
__device__ __forceinline__ float gelu_fast(float x) {
    float t = 1.5957691216057308f * x * (1.0f + 0.044715f * x * x);
    return x / (1.0f + __expf(-t));
}

// ---------------------------------------------------------------------------
// Fused embed + h-precompute for ALL layers (h depends only on X, which is
// constant across layers). grid (32 chunks, NB, NW) x 256 = 2048 blocks,
// NO LDS, NO barriers: pure VMEM-stream + FMA. Also writes X (l==0 blocks)
// and inits out=bias. Off the serial critical path by being one fat kernel.
__global__ __launch_bounds__(256) void k_hx(const int* __restrict__ data,
                                            const float* __restrict__ emb,
                                            const float* __restrict__ fw1,
                                            const float* __restrict__ fb1,
                                            const float* __restrict__ bf,
                                            float* __restrict__ hbuf,
                                            float* __restrict__ X,
                                            float* __restrict__ out) {
    int chunk = blockIdx.x, b = blockIdx.y, l = blockIdx.z;
    int tid = threadIdx.x;
    int n0 = chunk * 64;
    const float* w1 = fw1 + (size_t)l * NDIM * NHID;
    const float* b1 = fb1 + (size_t)l * NHID;

    int kgrp = tid & 15, rgrp = tid >> 4;     // 16 k-groups x 16 row-groups
    int k0 = kgrp * 8, r0 = rgrp * 4;
    int idx[4];
#pragma unroll
    for (int rr = 0; rr < 4; ++rr) idx[rr] = data[b * NVEC + n0 + r0 + rr];

    float acc[4][8];
    {
        float4 bv0 = *(const float4*)&b1[k0];
        float4 bv1 = *(const float4*)&b1[k0 + 4];
        float bk[8] = {bv0.x, bv0.y, bv0.z, bv0.w, bv1.x, bv1.y, bv1.z, bv1.w};
#pragma unroll
        for (int rr = 0; rr < 4; ++rr)
#pragma unroll
            for (int j = 0; j < 8; ++j) acc[rr][j] = bk[j];
    }
#pragma unroll 2
    for (int d = 0; d < NDIM; d += 4) {
        float4 xr[4];
#pragma unroll
        for (int rr = 0; rr < 4; ++rr)
            xr[rr] = *(const float4*)&emb[(size_t)idx[rr] * NDIM + d];   // L2 gather
#pragma unroll
        for (int dd = 0; dd < 4; ++dd) {
            float4 wa = *(const float4*)&w1[(d + dd) * NHID + k0];       // L1-hot
            float4 wb = *(const float4*)&w1[(d + dd) * NHID + k0 + 4];
            float wk[8] = {wa.x, wa.y, wa.z, wa.w, wb.x, wb.y, wb.z, wb.w};
#pragma unroll
            for (int rr = 0; rr < 4; ++rr) {
                float xv = ((const float*)&xr[rr])[dd];
#pragma unroll
                for (int j = 0; j < 8; ++j) acc[rr][j] += xv * wk[j];
            }
        }
    }
    float* hp = hbuf + (size_t)l * HSLICE + ((size_t)b * NVEC + n0 + r0) * NHID + k0;
#pragma unroll
    for (int rr = 0; rr < 4; ++rr) {
        float4 o0, o1;
        o0.x = gelu_fast(acc[rr][0]); o0.y = gelu_fast(acc[rr][1]);
        o0.z = gelu_fast(acc[rr][2]); o0.w = gelu_fast(acc[rr][3]);
        o1.x = gelu_fast(acc[rr][4]); o1.y = gelu_fast(acc[rr][5]);
        o1.z = gelu_fast(acc[rr][6]); o1.w = gelu_fast(acc[rr][7]);
        *(float4*)(hp + rr * NHID)     = o0;
        *(float4*)(hp + rr * NHID + 4) = o1;
    }
    if (l == 0) {   // write X (= initial V) as byproduct
        float4* Xo = (float4*)(X + ((size_t)b * NVEC + n0) * NDIM);
#pragma unroll
        for (int j = 0; j < 2; ++j) {
            int i4 = tid + j * 256;             // 512 f4 = 64 rows x 32 d
            int r = i4 >> 3, c = i4 & 7;
            Xo[i4] = ((const float4*)emb)[(size_t)data[b * NVEC + n0 + r] * 8 + c];
        }
        if (chunk == 0 && b == 0 && tid < NB * NCLASS)
            out[tid] = bf[tid % NCLASS];
    }
}

// ---------------------------------------------------------------------------
// Partial U = fw2 @ V, m-split 64. grid (MS, NB) x 256 = 512 blocks (2/CU,
// 8 waves/CU). ZERO LDS, zero barriers: both matmul dims lane-spanned, so
// fw2 reads are per-lane (wave-coalesced across 8 k-groups) and V reads are
// per-lane contiguous (full 128B row per instr, broadcast across k-groups).
// 8 VMEM per 64 FMA-instr. Bias-row partial folded in (lanes 0..31 of wave0).
__global__ __launch_bounds__(256) void k_U(const float* __restrict__ V,
                                           const float* __restrict__ fw2,
                                           const float* __restrict__ fb2,
                                           float* __restrict__ Upart) {
    int ms = blockIdx.x, b = blockIdx.y;
    int tid = threadIdx.x, lane = tid & 63, w = tid >> 6;
    int m0 = ms * 64;
    int kgrp = lane & 7, dgrp = lane >> 3;
    int k0 = w * 32 + kgrp * 4, d0 = dgrp * 4;
    const float* Vb = V + ((size_t)b * NVEC + m0) * NDIM;

    float acc[4][4];
#pragma unroll
    for (int kk = 0; kk < 4; ++kk)
#pragma unroll
        for (int j = 0; j < 4; ++j) acc[kk][j] = 0.f;

#pragma unroll 4
    for (int mm = 0; mm < 64; mm += 4) {
        float4 wr[4], vr[4];
#pragma unroll
        for (int kk = 0; kk < 4; ++kk)
            wr[kk] = *(const float4*)&fw2[(size_t)(k0 + kk) * NVEC + m0 + mm];
#pragma unroll
        for (int j = 0; j < 4; ++j)
            vr[j] = *(const float4*)&Vb[(mm + j) * NDIM + d0];
#pragma unroll
        for (int kk = 0; kk < 4; ++kk) {
            const float* wf = (const float*)&wr[kk];
#pragma unroll
            for (int j = 0; j < 4; ++j) {
                float wv = wf[j];
                acc[kk][0] += wv * vr[j].x;
                acc[kk][1] += wv * vr[j].y;
                acc[kk][2] += wv * vr[j].z;
                acc[kk][3] += wv * vr[j].w;
            }
        }
    }
    float* Up = Upart + ((size_t)ms * NB + b) * USIZE;
#pragma unroll
    for (int kk = 0; kk < 4; ++kk)
        *(float4*)&Up[(k0 + kk) * 32 + d0] =
            make_float4(acc[kk][0], acc[kk][1], acc[kk][2], acc[kk][3]);
    if (tid < 32) {     // bias-row partial: sum_m fb2[m0+m] * V[m][d]
        float ca = 0.f;
#pragma unroll 8
        for (int mm = 0; mm < 64; ++mm)
            ca += fb2[m0 + mm] * Vb[mm * NDIM + tid];
        Up[128 * 32 + tid] = ca;
    }
}

// ---------------------------------------------------------------------------
// Reduce MS partials into final U (incl. bias row). grid (NB, 5) x 256.
__global__ __launch_bounds__(256) void k_Ured(const float* __restrict__ Upart,
                                              float* __restrict__ U) {
    int b = blockIdx.x;
    int i4 = blockIdx.y * 256 + threadIdx.x;       // USIZE/4 = 1032
    if (i4 >= USIZE / 4) return;
    float4 s = ((const float4*)(Upart + (size_t)b * USIZE))[i4];
#pragma unroll
    for (int ms = 1; ms < MS; ++ms) {
        float4 v = ((const float4*)(Upart + ((size_t)ms * NB + b) * USIZE))[i4];
        s.x += v.x; s.y += v.y; s.z += v.z; s.w += v.w;
    }
    ((float4*)(U + (size_t)b * USIZE))[i4] = s;
}

// ---------------------------------------------------------------------------
// V_new = h @ U + Ubias. grid (NVEC/64, NB) x 256 = 512 blocks (2/CU,
// 8 waves/CU). ZERO LDS in the hot path, zero barriers (except tiny LAST
// reduce). h streamed from global once (16 MB); U (16.5 KB/b) L2/L3-hot,
// wave-coalesced: h per-lane rows (8 distinct x 16B), U full-row 128B/instr.
// 6 VMEM per 32 FMA-instr. LAST: classifier fused.
template <bool LAST>
__global__ __launch_bounds__(256) void k_apply(const float* __restrict__ hl,
                                               const float* __restrict__ U,
                                               float* __restrict__ Vout,
                                               const float* __restrict__ Wf,
                                               float* __restrict__ out) {
    __shared__ float ored[4][NCLASS];              // LAST only, 160 B
    int ng = blockIdx.x, b = blockIdx.y;
    int tid = threadIdx.x, lane = tid & 63, w = tid >> 6;
    int n0 = ng * 64;
    int dgrp = lane & 7, rgrp = lane >> 3;
    int d0 = dgrp * 4;
    int row = n0 + w * 16 + rgrp * 2;              // this thread: rows row, row+1
    const float* Ub = U + (size_t)b * USIZE;
    const float* h0 = hl + ((size_t)b * NVEC + row) * NHID;
    const float* h1 = h0 + NHID;

    float4 a0 = *(const float4*)&Ub[128 * 32 + d0];    // bias row
    float4 a1 = a0;
#pragma unroll 4
    for (int k = 0; k < NHID; k += 4) {
        float4 hq0 = *(const float4*)&h0[k];
        float4 hq1 = *(const float4*)&h1[k];
        float4 u0 = *(const float4*)&Ub[(k + 0) * 32 + d0];
        float4 u1 = *(const float4*)&Ub[(k + 1) * 32 + d0];
        float4 u2 = *(const float4*)&Ub[(k + 2) * 32 + d0];
        float4 u3 = *(const float4*)&Ub[(k + 3) * 32 + d0];
        a0.x += hq0.x * u0.x + hq0.y * u1.x + hq0.z * u2.x + hq0.w * u3.x;
        a0.y += hq0.x * u0.y + hq0.y * u1.y + hq0.z * u2.y + hq0.w * u3.y;
        a0.z += hq0.x * u0.z + hq0.y * u1.z + hq0.z * u2.z + hq0.w * u3.z;
        a0.w += hq0.x * u0.w + hq0.y * u1.w + hq0.z * u2.w + hq0.w * u3.w;
        a1.x += hq1.x * u0.x + hq1.y * u1.x + hq1.z * u2.x + hq1.w * u3.x;
        a1.y += hq1.x * u0.y + hq1.y * u1.y + hq1.z * u2.y + hq1.w * u3.y;
        a1.z += hq1.x * u0.z + hq1.y * u1.z + hq1.z * u2.z + hq1.w * u3.z;
        a1.w += hq1.x * u0.w + hq1.y * u1.w + hq1.z * u2.w + hq1.w * u3.w;
    }
    if constexpr (!LAST) {
        float* vo = Vout + ((size_t)b * NVEC + row) * NDIM + d0;
        *(float4*)vo          = a0;
        *(float4*)(vo + NDIM) = a1;
    } else {
        float accC[NCLASS];
#pragma unroll
        for (int c = 0; c < NCLASS; ++c) accC[c] = 0.f;
        float va[2][4] = {{a0.x, a0.y, a0.z, a0.w}, {a1.x, a1.y, a1.z, a1.w}};
#pragma unroll
        for (int r = 0; r < 2; ++r)
#pragma unroll
            for (int dd = 0; dd < 4; ++dd) {
                size_t j = (size_t)(row + r) * NDIM + d0 + dd;
                const float2* wr = (const float2*)(Wf + j * NCLASS);
                float v = va[r][dd];
#pragma unroll
                for (int p = 0; p < 5; ++p) {
                    float2 wv = wr[p];
                    accC[2 * p]     += v * wv.x;
                    accC[2 * p + 1] += v * wv.y;
                }
            }
#pragma unroll
        for (int c = 0; c < NCLASS; ++c)
#pragma unroll
            for (int off = 32; off >= 1; off >>= 1)
                accC[c] += __shfl_down(accC[c], off, 64);
        if (lane == 0) {
#pragma unroll
            for (int c = 0; c < NCLASS; ++c) ored[w][c] = accC[c];
        }
        __syncthreads();
        if (tid < NCLASS)
            atomicAdd(&out[b * NCLASS + tid],
                      ored[0][tid] + ored[1][tid] + ored[2][tid] + ored[3][tid]);
    }
}

// ---------------------------------------------------------------------------
extern "C" void kernel_launch(void* const* d_in, const int* in_sizes, int n_in,
                              void* d_out, int out_size, void* d_ws, size_t ws_size,
                              hipStream_t stream) {
    const int*   data = (const int*)d_in[0];
    const float* emb  = (const float*)d_in[1];
    const float* fw1  = (const float*)d_in[2];
    const float* fb1  = (const float*)d_in[3];
    const float* fw2  = (const float*)d_in[4];
    const float* fb2  = (const float*)d_in[5];
    const float* Wf   = (const float*)d_in[6];
    const float* bf   = (const float*)d_in[7];
    float* out = (float*)d_out;

    float* X     = (float*)d_ws;                      // 1048576 floats
    float* VA    = X + (size_t)NB * NVEC * NDIM;      // 1048576
    float* VB    = VA + (size_t)NB * NVEC * NDIM;     // 1048576
    float* Upart = VB + (size_t)NB * NVEC * NDIM;     // MS*NB*USIZE = 2113536
    float* U     = Upart + (size_t)MS * NB * USIZE;   // NB*USIZE = 66048
    float* hbuf  = U + (size_t)NB * USIZE;            // NW*HSLICE = 16777216 (~84MB total)

    // embed + all-layer h precompute (h depends only on X, constant per layer)
    k_hx<<<dim3(NVEC / 64, NB, NW), 256, 0, stream>>>(data, emb, fw1, fb1, bf,
                                                      hbuf, X, out);

    const float* Vcur = X;
    float* Vnext = VA;
    for (int t = 0; t < NW; ++t) {
        int i = NW - 1 - t;
        k_U<<<dim3(MS, NB), 256, 0, stream>>>(Vcur, fw2 + (size_t)i * NHID * NVEC,
                                              fb2 + (size_t)i * NVEC, Upart);
        k_Ured<<<dim3(NB, 5), 256, 0, stream>>>(Upart, U);
        const float* hl = hbuf + (size_t)i * HSLICE;
        if (i > 0) {
            k_apply<false><<<dim3(NVEC / 64, NB), 256, 0, stream>>>(
                hl, U, Vnext, nullptr, nullptr);
            Vcur = Vnext;
            Vnext = (Vnext == VA) ? VB : VA;
        } else {
            k_apply<true><<<dim3(NVEC / 64, NB), 256, 0, stream>>>(
                hl, U, nullptr, Wf, out);
        }
    }
}

// Round 6
// 174.511 us; speedup vs baseline: 1.7475x; 1.7475x over previous
//
#include <hip/hip_runtime.h>

#define NB 16
#define NVEC 2048
#define NDIM 32
#define NW 4
#define NHID 128
#define NCLASS 10
#define NG 32               // 64-row chunks per b = U-partial slots
#define USIZE (129 * 32)    // U per b: rows 0..127 = fw2@V, row 128 = fb2^T@V

// tanh-approx GELU; validated absmax vs ref in prior sessions.
__device__ __forceinline__ float gelu_fast(float x) {
    float t = 1.5957691216057308f * x * (1.0f + 0.044715f * x * x);
    return x / (1.0f + __expf(-t));
}

// ---------------------------------------------------------------------------
// Phase C (shared): Upart[k][d] += fw2s[k][m] * vs[m][d] over this block's
// 64 m-rows; bias row from fb2 (global, uniform) * vs. Thread = 4k(interleaved,
// kg=lane-contig -> 2-way max on fw2s stride-68 rows) x 4d (vs broadcast).
// 8 LDS instr per 64 FMA-instr.
__device__ __forceinline__ void upart_phase(const float* __restrict__ vs,
                                            const float* __restrict__ fw2s,
                                            const float* __restrict__ fb2l,
                                            int n0, int tid,
                                            float* __restrict__ Up) {
    int kg = tid & 31, d0 = (tid >> 5) * 4;
    float acc[4][4];
#pragma unroll
    for (int i = 0; i < 4; ++i)
#pragma unroll
        for (int j = 0; j < 4; ++j) acc[i][j] = 0.f;
#pragma unroll 4
    for (int mm = 0; mm < 64; mm += 4) {
        float4 w[4], v[4];
#pragma unroll
        for (int i = 0; i < 4; ++i)
            w[i] = *(const float4*)&fw2s[(kg + 32 * i) * 68 + mm];
#pragma unroll
        for (int j = 0; j < 4; ++j)
            v[j] = *(const float4*)&vs[(mm + j) * 36 + d0];
#pragma unroll
        for (int i = 0; i < 4; ++i) {
            const float* wf = (const float*)&w[i];
#pragma unroll
            for (int j = 0; j < 4; ++j) {
                float wv = wf[j];
                acc[i][0] += wv * v[j].x; acc[i][1] += wv * v[j].y;
                acc[i][2] += wv * v[j].z; acc[i][3] += wv * v[j].w;
            }
        }
    }
#pragma unroll
    for (int i = 0; i < 4; ++i)
        *(float4*)&Up[(kg + 32 * i) * 32 + d0] =
            make_float4(acc[i][0], acc[i][1], acc[i][2], acc[i][3]);
    if (tid < 32) {
        float ca = 0.f;
#pragma unroll 8
        for (int mm = 0; mm < 64; ++mm)
            ca += fb2l[n0 + mm] * vs[mm * 36 + tid];
        Up[128 * 32 + tid] = ca;
    }
}

// ---------------------------------------------------------------------------
// Embed gather (each emb row read ONCE, full 128B line -- R5 post-mortem:
// chunked re-gather cost ~1GB of L2 transactions) + X write + U-partials for
// the FIRST applied layer (fw2[3] @ X) + out=bias init. grid (NG, NB) x 256.
__global__ __launch_bounds__(256) void k_emb(const int* __restrict__ data,
                                             const float* __restrict__ emb,
                                             const float* __restrict__ fw2l,
                                             const float* __restrict__ fb2l,
                                             const float* __restrict__ bf,
                                             float* __restrict__ X,
                                             float* __restrict__ Upart,
                                             float* __restrict__ out) {
    __shared__ float vs[64 * 36];        // [m][d] pad 36
    __shared__ float fw2s[128 * 68];     // [k][m] pad 68
    int ng = blockIdx.x, b = blockIdx.y, tid = threadIdx.x;
    int n0 = ng * 64;
#pragma unroll
    for (int j = 0; j < 2; ++j) {
        int i = tid + j * 256;
        int r = i >> 3, c4 = (i & 7) * 4;
        int idx = data[b * NVEC + n0 + r];
        float4 v = *(const float4*)&emb[(size_t)idx * NDIM + c4];
        *(float4*)&vs[r * 36 + c4] = v;
        *(float4*)&X[((size_t)b * NVEC + n0 + r) * NDIM + c4] = v;
    }
#pragma unroll
    for (int j = 0; j < 8; ++j) {
        int i = tid + j * 256;
        int k = i >> 4, c4 = (i & 15) * 4;
        *(float4*)&fw2s[k * 68 + c4] =
            *(const float4*)&fw2l[(size_t)k * NVEC + n0 + c4];
    }
    if (ng == 0 && b == 0 && tid < NB * NCLASS)
        out[tid] = bf[tid % NCLASS];
    __syncthreads();
    upart_phase(vs, fw2s, fb2l, n0, tid, Upart + ((size_t)ng * NB + b) * USIZE);
}

// ---------------------------------------------------------------------------
// Reduce NG partial slots into final U. grid (NB, 5) x 256. Independent loads.
__global__ __launch_bounds__(256) void k_Ured(const float* __restrict__ Upart,
                                              float* __restrict__ U) {
    int b = blockIdx.x;
    int i4 = blockIdx.y * 256 + threadIdx.x;       // USIZE/4 = 1032
    if (i4 >= USIZE / 4) return;
    float4 s = ((const float4*)(Upart + (size_t)b * USIZE))[i4];
#pragma unroll
    for (int ms = 1; ms < NG; ++ms) {
        float4 v = ((const float4*)(Upart + ((size_t)ms * NB + b) * USIZE))[i4];
        s.x += v.x; s.y += v.y; s.z += v.z; s.w += v.w;
    }
    ((float4*)(U + (size_t)b * USIZE))[i4] = s;
}

// ---------------------------------------------------------------------------
// Fused layer step: h = gelu(X@fw1+b1) -> V' = h@U + ub -> (mid) next-layer
// U-partials from V' IN LDS (V' never touches global!) or (last) classifier.
// grid (NG, NB) x 256, LDS 75.8 KB -> 2 blocks/CU, 8 waves.
template <bool LAST>
__global__ __launch_bounds__(256) void k_apply(const float* __restrict__ X,
                                               const float* __restrict__ fw1l,
                                               const float* __restrict__ fb1l,
                                               const float* __restrict__ U,
                                               const float* __restrict__ fw2n,
                                               const float* __restrict__ fb2n,
                                               float* __restrict__ Upart,
                                               const float* __restrict__ Wf,
                                               float* __restrict__ out) {
    __shared__ float xs[64 * 36];        // X rows; then merge buf; then V'
    __shared__ float w1s[32 * 132];      // [d][k] pad 132
    __shared__ float hsb[128 * 68];      // h as [64r][132k-stride]; then fw2n [128][68]
    __shared__ float Us[USIZE];          // U linear, broadcast reads
    __shared__ float ored[4][NCLASS];
    int ng = blockIdx.x, b = blockIdx.y, tid = threadIdx.x;
    int n0 = ng * 64;

    // ---- stage X rows, w1, U
#pragma unroll
    for (int j = 0; j < 2; ++j) {
        int i = tid + j * 256;
        int r = i >> 3, c4 = (i & 7) * 4;
        *(float4*)&xs[r * 36 + c4] =
            *(const float4*)&X[((size_t)b * NVEC + n0 + r) * NDIM + c4];
    }
#pragma unroll
    for (int j = 0; j < 4; ++j) {
        int i = tid + j * 256;
        int d = i >> 5, c4 = (i & 31) * 4;
        *(float4*)&w1s[d * 132 + c4] = *(const float4*)&fw1l[d * NHID + c4];
    }
    for (int i4 = tid; i4 < USIZE / 4; i4 += 256)
        ((float4*)Us)[i4] = ((const float4*)(U + (size_t)b * USIZE))[i4];
    __syncthreads();

    int rg = tid & 31;                       // lane-contiguous row id
    {   // ---- h: thread = rows {rg, rg+32} x 16 k (k0 uniform per half-wave)
        int k0 = (tid >> 5) * 16;
        float acc[2][16];
        {
            float4 bq[4];
#pragma unroll
            for (int q = 0; q < 4; ++q) bq[q] = *(const float4*)&fb1l[k0 + 4 * q];
#pragma unroll
            for (int q = 0; q < 4; ++q) {
                acc[0][4 * q + 0] = bq[q].x; acc[0][4 * q + 1] = bq[q].y;
                acc[0][4 * q + 2] = bq[q].z; acc[0][4 * q + 3] = bq[q].w;
                acc[1][4 * q + 0] = bq[q].x; acc[1][4 * q + 1] = bq[q].y;
                acc[1][4 * q + 2] = bq[q].z; acc[1][4 * q + 3] = bq[q].w;
            }
        }
#pragma unroll 4
        for (int d = 0; d < NDIM; ++d) {
            float x0 = xs[rg * 36 + d];
            float x1 = xs[(rg + 32) * 36 + d];
            const float* wrow = &w1s[d * 132 + k0];          // broadcast
            float4 w0 = *(const float4*)wrow;
            float4 w1 = *(const float4*)(wrow + 4);
            float4 w2 = *(const float4*)(wrow + 8);
            float4 w3 = *(const float4*)(wrow + 12);
            float wk[16] = {w0.x, w0.y, w0.z, w0.w, w1.x, w1.y, w1.z, w1.w,
                            w2.x, w2.y, w2.z, w2.w, w3.x, w3.y, w3.z, w3.w};
#pragma unroll
            for (int j = 0; j < 16; ++j) {
                acc[0][j] += x0 * wk[j];
                acc[1][j] += x1 * wk[j];
            }
        }
#pragma unroll
        for (int r = 0; r < 2; ++r) {
            int row = rg + 32 * r;
#pragma unroll
            for (int q = 0; q < 4; ++q) {
                float4 o;
                o.x = gelu_fast(acc[r][4 * q + 0]);
                o.y = gelu_fast(acc[r][4 * q + 1]);
                o.z = gelu_fast(acc[r][4 * q + 2]);
                o.w = gelu_fast(acc[r][4 * q + 3]);
                *(float4*)&hsb[row * 132 + k0 + 4 * q] = o;
            }
        }
    }
    __syncthreads();

    // ---- apply: thread = rows {rg, rg+32} x 8 d x k-half
    int dg = (tid >> 5) & 3, kh = tid >> 7;
    int d0 = dg * 8, kb = kh * 64;
    float a[2][8];
#pragma unroll
    for (int r = 0; r < 2; ++r)
#pragma unroll
        for (int j = 0; j < 8; ++j) a[r][j] = 0.f;
#pragma unroll 4
    for (int ks = 0; ks < 64; ks += 4) {
        int kk = kb + ks;
        float4 h0 = *(const float4*)&hsb[rg * 132 + kk];
        float4 h1 = *(const float4*)&hsb[(rg + 32) * 132 + kk];
        float4 u[4][2];
#pragma unroll
        for (int j = 0; j < 4; ++j) {
            u[j][0] = *(const float4*)&Us[(kk + j) * 32 + d0];       // broadcast
            u[j][1] = *(const float4*)&Us[(kk + j) * 32 + d0 + 4];
        }
        const float* hf0 = (const float*)&h0;
        const float* hf1 = (const float*)&h1;
#pragma unroll
        for (int j = 0; j < 4; ++j) {
            float v0 = hf0[j], v1 = hf1[j];
            a[0][0] += v0 * u[j][0].x; a[0][1] += v0 * u[j][0].y;
            a[0][2] += v0 * u[j][0].z; a[0][3] += v0 * u[j][0].w;
            a[0][4] += v0 * u[j][1].x; a[0][5] += v0 * u[j][1].y;
            a[0][6] += v0 * u[j][1].z; a[0][7] += v0 * u[j][1].w;
            a[1][0] += v1 * u[j][0].x; a[1][1] += v1 * u[j][0].y;
            a[1][2] += v1 * u[j][0].z; a[1][3] += v1 * u[j][0].w;
            a[1][4] += v1 * u[j][1].x; a[1][5] += v1 * u[j][1].y;
            a[1][6] += v1 * u[j][1].z; a[1][7] += v1 * u[j][1].w;
        }
    }
    if (kh == 1) {   // publish k-half-1 partials (xs dead after h)
#pragma unroll
        for (int r = 0; r < 2; ++r) {
            float* p = &xs[(rg + 32 * r) * 36 + d0];
            *(float4*)p       = make_float4(a[r][0], a[r][1], a[r][2], a[r][3]);
            *(float4*)(p + 4) = make_float4(a[r][4], a[r][5], a[r][6], a[r][7]);
        }
    }
    __syncthreads();                         // apply reads of hsb done too

    if constexpr (!LAST) {                   // stage next-layer fw2 into hsb
#pragma unroll
        for (int j = 0; j < 8; ++j) {
            int i = tid + j * 256;
            int k = i >> 4, c4 = (i & 15) * 4;
            *(float4*)&hsb[k * 68 + c4] =
                *(const float4*)&fw2n[(size_t)k * NVEC + n0 + c4];
        }
    }
    if (kh == 0) {   // merge halves + U bias row -> final V' into xs
        float4 ub0 = *(const float4*)&Us[128 * 32 + d0];
        float4 ub1 = *(const float4*)&Us[128 * 32 + d0 + 4];
#pragma unroll
        for (int r = 0; r < 2; ++r) {
            float* p = &xs[(rg + 32 * r) * 36 + d0];
            float4 p0 = *(const float4*)p;
            float4 p1 = *(const float4*)(p + 4);
            a[r][0] += p0.x + ub0.x; a[r][1] += p0.y + ub0.y;
            a[r][2] += p0.z + ub0.z; a[r][3] += p0.w + ub0.w;
            a[r][4] += p1.x + ub1.x; a[r][5] += p1.y + ub1.y;
            a[r][6] += p1.z + ub1.z; a[r][7] += p1.w + ub1.w;
            *(float4*)p       = make_float4(a[r][0], a[r][1], a[r][2], a[r][3]);
            *(float4*)(p + 4) = make_float4(a[r][4], a[r][5], a[r][6], a[r][7]);
        }
    }
    __syncthreads();                         // V' (xs) + fw2s (hsb) ready

    if constexpr (!LAST) {
        upart_phase(xs, hsb, fb2n, n0, tid,
                    Upart + ((size_t)ng * NB + b) * USIZE);
    } else {
        // classifier: out[b,c] += sum V'[n,d] * Wf[n*32+d, c]
        float accC[NCLASS];
#pragma unroll
        for (int c = 0; c < NCLASS; ++c) accC[c] = 0.f;
        if (kh == 0) {
#pragma unroll
            for (int r = 0; r < 2; ++r) {
                int nrow = n0 + rg + 32 * r;
#pragma unroll
                for (int dd = 0; dd < 8; ++dd) {
                    float v = a[r][dd];
                    const float2* wr =
                        (const float2*)(Wf + ((size_t)nrow * 32 + d0 + dd) * NCLASS);
#pragma unroll
                    for (int p = 0; p < 5; ++p) {
                        float2 w = wr[p];
                        accC[2 * p]     += v * w.x;
                        accC[2 * p + 1] += v * w.y;
                    }
                }
            }
        }
#pragma unroll
        for (int c = 0; c < NCLASS; ++c)
#pragma unroll
            for (int off = 32; off >= 1; off >>= 1)
                accC[c] += __shfl_down(accC[c], off, 64);
        int w = tid >> 6;
        if ((tid & 63) == 0) {
#pragma unroll
            for (int c = 0; c < NCLASS; ++c) ored[w][c] = accC[c];
        }
        __syncthreads();
        if (tid < NCLASS)
            atomicAdd(&out[b * NCLASS + tid],
                      ored[0][tid] + ored[1][tid] + ored[2][tid] + ored[3][tid]);
    }
}

// ---------------------------------------------------------------------------
extern "C" void kernel_launch(void* const* d_in, const int* in_sizes, int n_in,
                              void* d_out, int out_size, void* d_ws, size_t ws_size,
                              hipStream_t stream) {
    const int*   data = (const int*)d_in[0];
    const float* emb  = (const float*)d_in[1];
    const float* fw1  = (const float*)d_in[2];
    const float* fb1  = (const float*)d_in[3];
    const float* fw2  = (const float*)d_in[4];
    const float* fb2  = (const float*)d_in[5];
    const float* Wf   = (const float*)d_in[6];
    const float* bf   = (const float*)d_in[7];
    float* out = (float*)d_out;

    float* X     = (float*)d_ws;                      // 1048576 floats
    float* Upart = X + (size_t)NB * NVEC * NDIM;      // NG*NB*USIZE = 2113536
    float* U     = Upart + (size_t)NG * NB * USIZE;   // NB*USIZE = 66048

    // embed + X + U-partials for layer 3 (first applied layer)
    k_emb<<<dim3(NG, NB), 256, 0, stream>>>(data, emb, fw2 + 3 * (size_t)NHID * NVEC,
                                            fb2 + 3 * (size_t)NVEC, bf, X, Upart, out);
    k_Ured<<<dim3(NB, 5), 256, 0, stream>>>(Upart, U);

    for (int i = NW - 1; i >= 1; --i) {
        k_apply<false><<<dim3(NG, NB), 256, 0, stream>>>(
            X, fw1 + (size_t)i * NDIM * NHID, fb1 + (size_t)i * NHID, U,
            fw2 + (size_t)(i - 1) * NHID * NVEC, fb2 + (size_t)(i - 1) * NVEC,
            Upart, nullptr, nullptr);
        k_Ured<<<dim3(NB, 5), 256, 0, stream>>>(Upart, U);
    }
    k_apply<true><<<dim3(NG, NB), 256, 0, stream>>>(
        X, fw1, fb1, U, nullptr, nullptr, nullptr, Wf, out);
}